// Round 6
// baseline (592.757 us; speedup 1.0000x reference)
//
#include <hip/hip_runtime.h>
#include <math.h>

#define B_    16
#define N_    512
#define D_    256
#define H_    8
#define DH_   32
#define DFF_  1024
#define L_    2
#define NEG_INF_ (-1e9f)
#define LRELU_ 0.2f

typedef __attribute__((ext_vector_type(8))) short bf8_t;
typedef __attribute__((ext_vector_type(8))) unsigned short us8;
typedef __attribute__((ext_vector_type(4))) unsigned short us4;
typedef __attribute__((ext_vector_type(4))) float f4_t;

__device__ __forceinline__ unsigned short f2bf(float f) {
    union { float f; unsigned u; } v; v.f = f;
    unsigned r = v.u + 0x7FFF + ((v.u >> 16) & 1);
    return (unsigned short)(r >> 16);
}
__device__ __forceinline__ float bf2f(unsigned short h) {
    union { unsigned u; float f; } v; v.u = ((unsigned)h) << 16;
    return v.f;
}

__device__ __forceinline__ void gl_lds16(const void* g, void* l) {
    __builtin_amdgcn_global_load_lds(
        (const __attribute__((address_space(1))) unsigned int*)g,
        (__attribute__((address_space(3))) unsigned int*)l, 16, 0, 0);
}

// ============ bf16 MFMA GEMM: C = act(scale * A @ Bt^T + bias) ==============
// A: [M x K] bf16 row-major; Bt: [N x K] bf16 row-major (k contiguous)
// out: Cf (f32) and/or Ch (bf16); trans=1 -> Ch[col*ldc + row] (bf16 only)
// act: 0=none 1=relu 2=elu 3=elu->*sqrt(D)+positional-encoding (fused scale_pe;
//      requires row0+r == token index within sequence, i.e. BM tiles within one batch)
// 2-phase double-buffered K-loop: STAGE(t+1) issued before compute(t),
// single barrier per K-step. Tile shape chosen per-call so grid >= 256 blocks.
template <int BM, int BN, int WROWS, int WCOLS>
__global__ __launch_bounds__(256) void mfma_gemm(
    const unsigned short* __restrict__ Ag, const unsigned short* __restrict__ Btg,
    const float* __restrict__ bias,
    float* __restrict__ Cfg, unsigned short* __restrict__ Chg, int trans,
    int K, int lda, int ldb, int ldc,
    int inner, long sAo, long sAi, long sBo, long sBi, long sCo, long sCi,
    float scale, int act)
{
    constexpr int TM = BM / WROWS, TN = BN / WCOLS;
    constexpr int MT = TM / 16, NT = TN / 16;

    int z  = blockIdx.z;
    int zo = z / inner;
    int zi = z - zo * inner;
    const unsigned short* Ab = Ag + (long)zo * sAo + (long)zi * sAi;
    const unsigned short* Bt = Btg + (long)zo * sBo + (long)zi * sBi;
    long co = (long)zo * sCo + (long)zi * sCi;

    int bm = blockIdx.y * BM;
    int bn = blockIdx.x * BN;
    int tid  = threadIdx.x;
    int lane = tid & 63;
    int w    = tid >> 6;
    int wr   = w / WCOLS, wc = w - wr * WCOLS;

    __shared__ unsigned short As[2][BM * 32];
    __shared__ unsigned short Bs[2][BN * 32];

    f4_t acc[MT][NT] = {};

    int lrow = lane & 15;
    int koff = (lane >> 4) * 8;

    auto stage = [&](int buf, int k0) {
#pragma unroll
        for (int t = w; t < BM / 16; t += 4) {
            int s = t * 512 + lane * 8;
            int r = s >> 5, c = s & 31;
            gl_lds16(Ab + (long)(bm + r) * lda + k0 + c, &As[buf][t * 512]);
        }
#pragma unroll
        for (int t = w; t < BN / 16; t += 4) {
            int s = t * 512 + lane * 8;
            int r = s >> 5, c = s & 31;
            gl_lds16(Bt + (long)(bn + r) * ldb + k0 + c, &Bs[buf][t * 512]);
        }
    };

    int nk = K >> 5;
    stage(0, 0);
    __syncthreads();

    for (int t = 0; t < nk; t++) {
        int cur = t & 1;
        if (t + 1 < nk) stage(cur ^ 1, (t + 1) << 5);

        bf8_t af[MT], bfr[NT];
#pragma unroll
        for (int mi = 0; mi < MT; mi++)
            af[mi] = *(const bf8_t*)&As[cur][(wr * TM + mi * 16 + lrow) * 32 + koff];
#pragma unroll
        for (int ni = 0; ni < NT; ni++)
            bfr[ni] = *(const bf8_t*)&Bs[cur][(wc * TN + ni * 16 + lrow) * 32 + koff];
#pragma unroll
        for (int mi = 0; mi < MT; mi++)
#pragma unroll
            for (int ni = 0; ni < NT; ni++)
                acc[mi][ni] = __builtin_amdgcn_mfma_f32_16x16x32_bf16(
                    af[mi], bfr[ni], acc[mi][ni], 0, 0, 0);
        __syncthreads();   // drains prefetch (vmcnt) + reads; buf swap safe
    }

#pragma unroll
    for (int mi = 0; mi < MT; mi++) {
#pragma unroll
        for (int ni = 0; ni < NT; ni++) {
            int row0 = bm + wr * TM + mi * 16 + (lane >> 4) * 4;
            int col  = bn + wc * TN + ni * 16 + (lane & 15);
            float bv = bias ? bias[col] : 0.f;
            float vv[4];
#pragma unroll
            for (int r = 0; r < 4; r++) {
                float v = acc[mi][ni][r] * scale + bv;
                if (act == 1) v = fmaxf(v, 0.f);
                else if (act == 2) v = v > 0.f ? v : (__expf(v) - 1.f);
                else if (act == 3) {
                    // elu -> x*sqrt(D) + PE (fused scale_pe; n = row0+r, d = col)
                    v = v > 0.f ? v : (__expf(v) - 1.f);
                    float expo = (float)(col & ~1) * (1.0f / D_);
                    float inv  = __expf(-expo * 9.210340371976184f);   // 10000^-expo
                    float ang  = (float)(row0 + r) * inv;
                    v = v * 16.0f + ((col & 1) ? cosf(ang) : sinf(ang));
                }
                vv[r] = v;
            }
            if (trans) {
                ushort4 u = make_ushort4(f2bf(vv[0]), f2bf(vv[1]), f2bf(vv[2]), f2bf(vv[3]));
                *(ushort4*)&Chg[co + (long)col * ldc + row0] = u;
            } else {
                if (Cfg) {
#pragma unroll
                    for (int r = 0; r < 4; r++)
                        Cfg[co + (long)(row0 + r) * ldc + col] = vv[r];
                }
                if (Chg) {
#pragma unroll
                    for (int r = 0; r < 4; r++)
                        Chg[co + (long)(row0 + r) * ldc + col] = f2bf(vv[r]);
                }
            }
        }
    }
}

// ==== fused GEMM + residual-add LayerNorm ====================================
// C = A @ Bt^T + bias ; v = C + resid ; out = LN_row(v) * g + beta
// BM=32, BN=256 (full rows per block) so the LN reduction is intra-block.
// grid = (M/32); 4 waves, each owns all 32 rows x 64 cols.
__global__ __launch_bounds__(256) void mfma_gemm_ln(
    const unsigned short* __restrict__ Ag, const unsigned short* __restrict__ Btg,
    const float* __restrict__ bias,
    const float* __restrict__ resid,
    const float* __restrict__ g, const float* __restrict__ beta,
    float* __restrict__ outf, unsigned short* __restrict__ outb,
    int K)
{
    int bm = blockIdx.x * 32;
    int tid = threadIdx.x, lane = tid & 63, w = tid >> 6;
    int lrow = lane & 15, quad = lane >> 4;
    int koff = quad * 8;

    __shared__ unsigned short As[2][32 * 32];
    __shared__ unsigned short Bs[2][256 * 32];
    __shared__ float rsum[4][32];
    __shared__ float rsq[4][32];

    f4_t acc[2][4] = {};

    auto stage = [&](int buf, int k0) {
        if (w < 2) {
            int s = w * 512 + lane * 8;
            int r = s >> 5, c = s & 31;
            gl_lds16(Ag + (long)(bm + r) * K + k0 + c, &As[buf][w * 512]);
        }
#pragma unroll
        for (int t = w; t < 16; t += 4) {
            int s = t * 512 + lane * 8;
            int r = s >> 5, c = s & 31;
            gl_lds16(Btg + (long)r * K + k0 + c, &Bs[buf][t * 512]);
        }
    };

    int nk = K >> 5;
    stage(0, 0);
    __syncthreads();
    for (int t = 0; t < nk; t++) {
        int cur = t & 1;
        if (t + 1 < nk) stage(cur ^ 1, (t + 1) << 5);
        bf8_t af[2], bfr[4];
#pragma unroll
        for (int mi = 0; mi < 2; mi++)
            af[mi] = *(const bf8_t*)&As[cur][(mi * 16 + lrow) * 32 + koff];
#pragma unroll
        for (int ni = 0; ni < 4; ni++)
            bfr[ni] = *(const bf8_t*)&Bs[cur][(w * 64 + ni * 16 + lrow) * 32 + koff];
#pragma unroll
        for (int mi = 0; mi < 2; mi++)
#pragma unroll
            for (int ni = 0; ni < 4; ni++)
                acc[mi][ni] = __builtin_amdgcn_mfma_f32_16x16x32_bf16(
                    af[mi], bfr[ni], acc[mi][ni], 0, 0, 0);
        __syncthreads();
    }

    // ---- v = C + bias + resid; per-row mean (two-pass LN, matches ln_add) ---
    float vv[2][4][4];
    float sp[2][4] = {};
#pragma unroll
    for (int mi = 0; mi < 2; mi++)
#pragma unroll
        for (int ni = 0; ni < 4; ni++) {
            int row = mi * 16 + quad * 4;
            int col = w * 64 + ni * 16 + lrow;
            float bcol = bias[col];
#pragma unroll
            for (int r = 0; r < 4; r++) {
                float v = acc[mi][ni][r] + bcol +
                          resid[(long)(bm + row + r) * 256 + col];
                vv[mi][ni][r] = v;
                sp[mi][r] += v;
            }
        }
#pragma unroll
    for (int mi = 0; mi < 2; mi++)
#pragma unroll
        for (int r = 0; r < 4; r++) {
            float s = sp[mi][r];
            s += __shfl_xor(s, 1); s += __shfl_xor(s, 2);
            s += __shfl_xor(s, 4); s += __shfl_xor(s, 8);
            sp[mi][r] = s;
        }
    if (lrow == 0) {
#pragma unroll
        for (int mi = 0; mi < 2; mi++)
#pragma unroll
            for (int r = 0; r < 4; r++)
                rsum[w][mi * 16 + quad * 4 + r] = sp[mi][r];
    }
    __syncthreads();
    float mean[2][4];
#pragma unroll
    for (int mi = 0; mi < 2; mi++)
#pragma unroll
        for (int r = 0; r < 4; r++) {
            int row = mi * 16 + quad * 4 + r;
            mean[mi][r] = (rsum[0][row] + rsum[1][row] + rsum[2][row] + rsum[3][row])
                          * (1.f / 256.f);
        }
    float qp[2][4] = {};
#pragma unroll
    for (int mi = 0; mi < 2; mi++)
#pragma unroll
        for (int ni = 0; ni < 4; ni++)
#pragma unroll
            for (int r = 0; r < 4; r++) {
                float d = vv[mi][ni][r] - mean[mi][r];
                qp[mi][r] += d * d;
            }
#pragma unroll
    for (int mi = 0; mi < 2; mi++)
#pragma unroll
        for (int r = 0; r < 4; r++) {
            float s = qp[mi][r];
            s += __shfl_xor(s, 1); s += __shfl_xor(s, 2);
            s += __shfl_xor(s, 4); s += __shfl_xor(s, 8);
            qp[mi][r] = s;
        }
    if (lrow == 0) {
#pragma unroll
        for (int mi = 0; mi < 2; mi++)
#pragma unroll
            for (int r = 0; r < 4; r++)
                rsq[w][mi * 16 + quad * 4 + r] = qp[mi][r];
    }
    __syncthreads();
    float rstd[2][4];
#pragma unroll
    for (int mi = 0; mi < 2; mi++)
#pragma unroll
        for (int r = 0; r < 4; r++) {
            int row = mi * 16 + quad * 4 + r;
            float var = (rsq[0][row] + rsq[1][row] + rsq[2][row] + rsq[3][row])
                        * (1.f / 256.f);
            rstd[mi][r] = rsqrtf(var + 1e-6f);
        }
#pragma unroll
    for (int mi = 0; mi < 2; mi++)
#pragma unroll
        for (int ni = 0; ni < 4; ni++) {
            int col = w * 64 + ni * 16 + lrow;
            float gc = g[col], bc2 = beta[col];
#pragma unroll
            for (int r = 0; r < 4; r++) {
                long orow = bm + mi * 16 + quad * 4 + r;
                float o = (vv[mi][ni][r] - mean[mi][r]) * rstd[mi][r] * gc + bc2;
                outf[orow * 256 + col] = o;
                if (outb) outb[orow * 256 + col] = f2bf(o);
            }
        }
}

// ============ fused attention: scores -> mask -> softmax -> PV ==============
// QKV: [B*N][768] bf16 (Q cols 0..255, K 256..511, V 512..767)
// one workgroup = (b,h) x 64-query tile; 4 waves x 16 rows.
template <bool WRITE_ATTN>
__global__ __launch_bounds__(256) void attn_fused(
    const unsigned short* __restrict__ QKV,
    const int* __restrict__ mask,
    float* __restrict__ attn_out,            // [B,H,N,N] f32
    unsigned short* __restrict__ Ob)         // [B*N][256] bf16
{
    int bh = blockIdx.x;
    int b  = bh >> 3, h = bh & 7;
    int q0 = blockIdx.y * 64;
    int tid  = threadIdx.x;
    int lane = tid & 63, w = tid >> 6;
    int lrow = lane & 15, quad = lane >> 4;

    __shared__ unsigned short Ks[512 * 40];   // K tile, row stride 40 (padded)
    __shared__ unsigned short Vs[32 * 136];   // V^T chunk, row stride 136
    __shared__ float maskf[512];
    unsigned short* Ps = Ks;                  // P staging aliases dead K tile

    const long tokbase = (long)b * N_;

    // ---- stage K tile [512][32] ----
#pragma unroll
    for (int i = 0; i < 8; i++) {
        int idx = tid + i * 256;
        int row = idx >> 2, seg = idx & 3;
        us8 v = *(const us8*)&QKV[(tokbase + row) * 768 + 256 + h * 32 + seg * 8];
        *(us8*)&Ks[row * 40 + seg * 8] = v;
    }
    maskf[tid]       = (float)mask[b * N_ + tid] * NEG_INF_;
    maskf[tid + 256] = (float)mask[b * N_ + tid + 256] * NEG_INF_;

    // ---- Q fragment (A-operand, one per wave-row-set) ----
    bf8_t aq = *(const bf8_t*)&QKV[(tokbase + q0 + w * 16 + lrow) * 768 + h * 32 + quad * 8];
    __syncthreads();

    // ---- S = Q @ K^T (16 rows x 512 cols per wave) ----
    f4_t acc[32];
    f4_t zero = {0.f, 0.f, 0.f, 0.f};
#pragma unroll
    for (int ni = 0; ni < 32; ni++) {
        bf8_t bk = *(const bf8_t*)&Ks[(ni * 16 + lrow) * 40 + quad * 8];
        acc[ni] = __builtin_amdgcn_mfma_f32_16x16x32_bf16(aq, bk, zero, 0, 0, 0);
    }

    // ---- scale + mask + softmax (rows live in (quad, reg)) ----
    const float rscale = 0.17677669529663687f;   // 1/sqrt(32)
    float mr[4] = {-3e38f, -3e38f, -3e38f, -3e38f};
#pragma unroll
    for (int ni = 0; ni < 32; ni++) {
        float mk = maskf[ni * 16 + lrow];
#pragma unroll
        for (int r = 0; r < 4; r++) {
            float v = acc[ni][r] * rscale + mk;
            acc[ni][r] = v;
            mr[r] = fmaxf(mr[r], v);
        }
    }
#pragma unroll
    for (int r = 0; r < 4; r++) {
        mr[r] = fmaxf(mr[r], __shfl_xor(mr[r], 1));
        mr[r] = fmaxf(mr[r], __shfl_xor(mr[r], 2));
        mr[r] = fmaxf(mr[r], __shfl_xor(mr[r], 4));
        mr[r] = fmaxf(mr[r], __shfl_xor(mr[r], 8));
    }
    float sr[4] = {0.f, 0.f, 0.f, 0.f};
#pragma unroll
    for (int ni = 0; ni < 32; ni++) {
#pragma unroll
        for (int r = 0; r < 4; r++) {
            float p = __expf(acc[ni][r] - mr[r]);
            acc[ni][r] = p;
            sr[r] += p;
        }
    }
#pragma unroll
    for (int r = 0; r < 4; r++) {
        sr[r] += __shfl_xor(sr[r], 1);
        sr[r] += __shfl_xor(sr[r], 2);
        sr[r] += __shfl_xor(sr[r], 4);
        sr[r] += __shfl_xor(sr[r], 8);
        sr[r] = 1.f / sr[r];
    }
#pragma unroll
    for (int ni = 0; ni < 32; ni++)
#pragma unroll
        for (int r = 0; r < 4; r++)
            acc[ni][r] *= sr[r];

    if (WRITE_ATTN) {
#pragma unroll
        for (int ni = 0; ni < 32; ni++) {
#pragma unroll
            for (int r = 0; r < 4; r++)
                attn_out[((long)bh * N_ + q0 + w * 16 + quad * 4 + r) * N_ + ni * 16 + lrow]
                    = acc[ni][r];
        }
    }

    // ---- O = P @ V, chunks of 128 keys ----
    f4_t oacc[2] = {{0.f,0.f,0.f,0.f}, {0.f,0.f,0.f,0.f}};
    int kk4 = (tid & 31) * 4;          // 4 consecutive keys
    int d0  = (tid >> 5) * 4;          // 4 consecutive d
    for (int c = 0; c < 4; c++) {
        __syncthreads();   // prev chunk MFMA done (and, at c=0, all Ks reads done)
        {   // stage V^T chunk: Vs[d][kk] = V[c*128+kk][d]
            // per-thread: 4 rows x 4 d -> 4x4 register transpose -> 4 ds_write_b64
            us4 vr[4];
#pragma unroll
            for (int i = 0; i < 4; i++)
                vr[i] = *(const us4*)&QKV[(tokbase + c * 128 + kk4 + i) * 768
                                          + 512 + h * 32 + d0];
#pragma unroll
            for (int jj = 0; jj < 4; jj++) {
                us4 wv = { vr[0][jj], vr[1][jj], vr[2][jj], vr[3][jj] };
                *(us4*)&Vs[(d0 + jj) * 136 + kk4] = wv;
            }
        }
        // write this wave's P chunk (wave-private region, C-layout -> A-layout)
#pragma unroll
        for (int ni = 0; ni < 8; ni++) {
            int nn = c * 8 + ni;
#pragma unroll
            for (int r = 0; r < 4; r++)
                Ps[w * 2176 + (quad * 4 + r) * 136 + ni * 16 + lrow] = f2bf(acc[nn][r]);
        }
        __syncthreads();
#pragma unroll
        for (int k8 = 0; k8 < 4; k8++) {
            bf8_t ap = *(const bf8_t*)&Ps[w * 2176 + lrow * 136 + k8 * 32 + quad * 8];
#pragma unroll
            for (int t = 0; t < 2; t++) {
                bf8_t bvf = *(const bf8_t*)&Vs[(t * 16 + lrow) * 136 + k8 * 32 + quad * 8];
                oacc[t] = __builtin_amdgcn_mfma_f32_16x16x32_bf16(ap, bvf, oacc[t], 0, 0, 0);
            }
        }
    }

#pragma unroll
    for (int t = 0; t < 2; t++)
#pragma unroll
        for (int r = 0; r < 4; r++)
            Ob[(tokbase + q0 + w * 16 + quad * 4 + r) * 256 + h * 32 + t * 16 + lrow]
                = f2bf(oacc[t][r]);
}

// ======== weight transpose + f32->bf16 conversion (+ bias pack, z==13) =======
struct ConvJobs {
    const float* src[13];
    unsigned short* dst[13];
    int R[13];
    int C[13];
    const float *bq, *bk, *bv;
    float* bc;
};

__global__ __launch_bounds__(256) void conv_transpose(ConvJobs j)
{
    int z = blockIdx.z;
    if (z == 13) {
        // pack bq|bk|bv -> bc [L][768] (one block's worth of work)
        if (blockIdx.x == 0 && blockIdx.y == 0) {
            for (int i = threadIdx.x; i < 2 * 768; i += 256) {
                int l = i / 768, c = i - l * 768;
                float v = (c < 256) ? j.bq[l * 256 + c]
                        : (c < 512) ? j.bk[l * 256 + c - 256]
                                    : j.bv[l * 256 + c - 512];
                j.bc[i] = v;
            }
        }
        return;
    }
    int R = j.R[z], C = j.C[z];
    int r0 = blockIdx.y * 64, c0 = blockIdx.x * 64;
    if (r0 >= R || c0 >= C) return;
    __shared__ float t[64][65];
    const float* src = j.src[z];
    unsigned short* dst = j.dst[z];
    int tx = threadIdx.x & 63, ty = threadIdx.x >> 6;
#pragma unroll
    for (int i = 0; i < 16; i++) {
        int r = ty + i * 4;
        t[r][tx] = src[(long)(r0 + r) * C + c0 + tx];
    }
    __syncthreads();
#pragma unroll
    for (int i = 0; i < 16; i++) {
        int c = ty + i * 4;
        dst[(long)(c0 + c) * R + r0 + tx] = f2bf(t[tx][c]);
    }
}

// ============ embedding gather -> Xb bf16 (f32 copy was dead) ================
__global__ __launch_bounds__(64) void gather_embed(const int* __restrict__ idx,
                                                   const float* __restrict__ embed,
                                                   unsigned short* __restrict__ Xb)
{
    int row = blockIdx.x;
    int id  = idx[row];
    float4 v = ((const float4*)(embed + (long)id * D_))[threadIdx.x];
    ((ushort4*)(Xb + (long)row * D_))[threadIdx.x] =
        make_ushort4(f2bf(v.x), f2bf(v.y), f2bf(v.z), f2bf(v.w));
}

// ============ GAT s1/s2 from transposed h (bf16 [D][B*N]) ====================
__global__ __launch_bounds__(256) void gat_s12T(const unsigned short* __restrict__ hT,
                                                const float* __restrict__ a1,
                                                const float* __restrict__ a2,
                                                float* __restrict__ s1,
                                                float* __restrict__ s2)
{
    int lane = threadIdx.x & 63;
    int dq   = threadIdx.x >> 6;
    int j = blockIdx.x * 64 + lane;
    float d1 = 0.f, d2 = 0.f;
#pragma unroll 8
    for (int d = dq * 64; d < dq * 64 + 64; d++) {
        float hv = bf2f(hT[(long)d * (B_ * N_) + j]);
        d1 += hv * a1[d];
        d2 += hv * a2[d];
    }
    __shared__ float r1[4][64], r2[4][64];
    r1[dq][lane] = d1;
    r2[dq][lane] = d2;
    __syncthreads();
    if (dq == 0) {
        s1[j] = r1[0][lane] + r1[1][lane] + r1[2][lane] + r1[3][lane];
        s2[j] = r2[0][lane] + r2[1][lane] + r2[2][lane] + r2[3][lane];
    }
}

// ============ GAT softmax row -> bf16 alpha ==================================
__global__ __launch_bounds__(256) void gat_alpha(const float* __restrict__ s1,
                                                 const float* __restrict__ s2,
                                                 const int* __restrict__ edges,
                                                 unsigned short* __restrict__ alpha)
{
    int row = blockIdx.x;
    int b   = row >> 9;
    const int*   erow = edges + (long)row * N_;
    const float* s2b  = s2 + (long)b * N_;
    float si = s1[row];
    int t = threadIdx.x;

    float e  = si + s2b[t];
    e = e > 0.f ? e : LRELU_ * e;
    float v0 = (erow[t] > 0) ? e : NEG_INF_;
    float e2 = si + s2b[t + 256];
    e2 = e2 > 0.f ? e2 : LRELU_ * e2;
    float v1 = (erow[t + 256] > 0) ? e2 : NEG_INF_;

    __shared__ float redm[4], reds[4];
    float m = fmaxf(v0, v1);
    for (int off = 32; off; off >>= 1) m = fmaxf(m, __shfl_xor(m, off));
    if ((t & 63) == 0) redm[t >> 6] = m;
    __syncthreads();
    m = fmaxf(fmaxf(redm[0], redm[1]), fmaxf(redm[2], redm[3]));
    float x0 = __expf(v0 - m), x1 = __expf(v1 - m);
    float s = x0 + x1;
    for (int off = 32; off; off >>= 1) s += __shfl_xor(s, off);
    if ((t & 63) == 0) reds[t >> 6] = s;
    __syncthreads();
    s = reds[0] + reds[1] + reds[2] + reds[3];
    float inv = 1.f / s;
    alpha[(long)row * N_ + t]       = f2bf(x0 * inv);
    alpha[(long)row * N_ + t + 256] = f2bf(x1 * inv);
}

// ============ driver =========================================================
extern "C" void kernel_launch(void* const* d_in, const int* in_sizes, int n_in,
                              void* d_out, int out_size, void* d_ws, size_t ws_size,
                              hipStream_t stream)
{
    const int*   node  = (const int*)d_in[0];
    const int*   edge  = (const int*)d_in[1];
    const int*   mask  = (const int*)d_in[2];
    const float* embed = (const float*)d_in[4];
    const float* Wg    = (const float*)d_in[5];
    const float* a1    = (const float*)d_in[6];
    const float* a2    = (const float*)d_in[7];
    const float* Wq    = (const float*)d_in[8];
    const float* bq    = (const float*)d_in[9];
    const float* Wk    = (const float*)d_in[10];
    const float* bk    = (const float*)d_in[11];
    const float* Wv    = (const float*)d_in[12];
    const float* bv    = (const float*)d_in[13];
    const float* Wo    = (const float*)d_in[14];
    const float* bo    = (const float*)d_in[15];
    const float* W1    = (const float*)d_in[16];
    const float* b1    = (const float*)d_in[17];
    const float* W2    = (const float*)d_in[18];
    const float* b2    = (const float*)d_in[19];
    const float* ln1g  = (const float*)d_in[20];
    const float* ln1b  = (const float*)d_in[21];
    const float* ln2g  = (const float*)d_in[22];
    const float* ln2b  = (const float*)d_in[23];

    const long XSZ = (long)B_ * N_ * D_;          // 2,097,152
    const int  MR  = B_ * N_;                     // 8192
    float* outx = (float*)d_out;
    float* ATT  = outx + XSZ;                     // [B,H,N,N] f32 (final attn)

    // ---- workspace layout ----
    float*          X    = (float*)d_ws;
    unsigned short* Xb   = (unsigned short*)(X + XSZ);
    float*          Hb   = (float*)(Xb + XSZ);
    unsigned short* alphab = (unsigned short*)Hb;             // GAT alpha aliases Hb
    unsigned short* QKVb = (unsigned short*)(Hb + XSZ);       // [8192][768] bf16
    unsigned short* hT   = QKVb;                              // GAT h^T aliases QKV
    unsigned short* Ob   = QKVb + (long)MR * 768;
    unsigned short* Fb   = Ob + XSZ;                          // [8192][1024] bf16
    float* S1 = (float*)(Fb + (long)MR * DFF_);
    float* S2 = S1 + MR;
    unsigned short* WgT = (unsigned short*)(S2 + MR);         // [256][256]
    unsigned short* Wc  = WgT + 65536;                        // [L][768][256]
    unsigned short* WoT = Wc + 2 * 768 * 256;                 // [L][256][256]
    unsigned short* W1T = WoT + 2 * 65536;                    // [L][1024][256]
    unsigned short* W2T = W1T + 2 * 262144;                   // [L][256][1024]
    float*          bc  = (float*)(W2T + 2 * 262144);         // [L][768]

    // ---- convert + transpose all weights to bf16 (+ bias pack as z=13) ----
    ConvJobs j;
    j.src[0] = Wg;  j.dst[0] = WgT;  j.R[0] = 256;  j.C[0] = 256;
    for (int l = 0; l < 2; l++) {
        j.src[1 + l] = Wq + l * 65536;  j.dst[1 + l] = Wc + l * 196608;           j.R[1+l] = 256;  j.C[1+l] = 256;
        j.src[3 + l] = Wk + l * 65536;  j.dst[3 + l] = Wc + l * 196608 + 65536;   j.R[3+l] = 256;  j.C[3+l] = 256;
        j.src[5 + l] = Wv + l * 65536;  j.dst[5 + l] = Wc + l * 196608 + 131072;  j.R[5+l] = 256;  j.C[5+l] = 256;
        j.src[7 + l] = Wo + l * 65536;  j.dst[7 + l] = WoT + l * 65536;           j.R[7+l] = 256;  j.C[7+l] = 256;
        j.src[9 + l] = W1 + l * 262144; j.dst[9 + l] = W1T + l * 262144;          j.R[9+l] = 256;  j.C[9+l] = 1024;
        j.src[11+ l] = W2 + l * 262144; j.dst[11+ l] = W2T + l * 262144;          j.R[11+l]= 1024; j.C[11+l]= 256;
    }
    j.bq = bq; j.bk = bk; j.bv = bv; j.bc = bc;
    conv_transpose<<<dim3(16, 16, 14), 256, 0, stream>>>(j);

    // ---- embedding (bf16 only; f32 copy was dead) ----
    gather_embed<<<MR, 64, 0, stream>>>(node, embed, Xb);

    // ---- GAT hops ----
    for (int hop = 0; hop < 2; hop++) {
        // h = X @ Wg -> hT (trans): 256 blocks
        mfma_gemm<64,128,1,4><<<dim3(2, 128, 1), 256, 0, stream>>>(
            Xb, WgT, nullptr, nullptr, hT, 1,
            256, 256, 256, MR, 1, 0,0, 0,0, 0,0, 1.f, 0);
        gat_s12T<<<128, 256, 0, stream>>>(hT, a1, a2, S1, S2);
        gat_alpha<<<MR, 256, 0, stream>>>(S1, S2, edge, alphab);
        // hop 0: x = elu(alpha @ h) -> Xb only (f32 X was dead)
        // hop 1: x = elu(alpha @ h)*sqrt(D) + PE -> X + Xb (fused scale_pe)
        if (hop == 0)
            mfma_gemm<64,128,1,4><<<dim3(2, 8, 16), 256, 0, stream>>>(
                alphab, hT, nullptr, nullptr, Xb, 0,
                512, 512, MR, 256, 1,
                (long)N_*N_, 0, (long)N_, 0, (long)N_*D_, 0, 1.f, 2);
        else
            mfma_gemm<64,128,1,4><<<dim3(2, 8, 16), 256, 0, stream>>>(
                alphab, hT, nullptr, X, Xb, 0,
                512, 512, MR, 256, 1,
                (long)N_*N_, 0, (long)N_, 0, (long)N_*D_, 0, 1.f, 3);
    }

    for (int l = 0; l < L_; l++) {
        // QKV combined projection: [8192][768] bf16; 768 blocks
        mfma_gemm<64,128,1,4><<<dim3(6, 128, 1), 256, 0, stream>>>(
            Xb, Wc + l * 196608, bc + l * 768, nullptr, QKVb, 0,
            256, 256, 256, 768, 1, 0,0, 0,0, 0,0, 1.f, 0);

        // fused attention (layer 1 also writes the attn output matrix)
        if (l == L_ - 1)
            attn_fused<true><<<dim3(128, 8, 1), 256, 0, stream>>>(QKVb, mask, ATT, Ob);
        else
            attn_fused<false><<<dim3(128, 8, 1), 256, 0, stream>>>(QKVb, mask, nullptr, Ob);

        // X = LN(X + O @ Wo + bo)  -- fused GEMM+LN, 256 blocks
        mfma_gemm_ln<<<dim3(MR / 32), 256, 0, stream>>>(
            Ob, WoT + l * 65536, bo + l * D_, X,
            ln1g + l * D_, ln1b + l * D_, X, Xb, 256);

        // F = relu(X @ W1 + b1)
        mfma_gemm<128,128,2,2><<<dim3(8, 64, 1), 256, 0, stream>>>(
            Xb, W1T + l * 262144, b1 + l * DFF_, nullptr, Fb, 0,
            256, 256, 256, 1024, 1, 0,0, 0,0, 0,0, 1.f, 1);
        // X = LN(X + F @ W2 + b2)  -- fused GEMM+LN (last layer -> d_out)
        if (l == L_ - 1)
            mfma_gemm_ln<<<dim3(MR / 32), 256, 0, stream>>>(
                Fb, W2T + l * 262144, b2 + l * D_, X,
                ln2g + l * D_, ln2b + l * D_, outx, nullptr, 1024);
        else
            mfma_gemm_ln<<<dim3(MR / 32), 256, 0, stream>>>(
                Fb, W2T + l * 262144, b2 + l * D_, X,
                ln2g + l * D_, ln2b + l * D_, X, Xb, 1024);
    }
}

// Round 7
// 531.194 us; speedup vs baseline: 1.1159x; 1.1159x over previous
//
#include <hip/hip_runtime.h>
#include <math.h>

#define B_    16
#define N_    512
#define D_    256
#define H_    8
#define DH_   32
#define DFF_  1024
#define L_    2
#define NEG_INF_ (-1e9f)
#define LRELU_ 0.2f

typedef __attribute__((ext_vector_type(8))) short bf8_t;
typedef __attribute__((ext_vector_type(8))) unsigned short us8;
typedef __attribute__((ext_vector_type(4))) unsigned short us4;
typedef __attribute__((ext_vector_type(4))) float f4_t;

__device__ __forceinline__ unsigned short f2bf(float f) {
    union { float f; unsigned u; } v; v.f = f;
    unsigned r = v.u + 0x7FFF + ((v.u >> 16) & 1);
    return (unsigned short)(r >> 16);
}
__device__ __forceinline__ float bf2f(unsigned short h) {
    union { unsigned u; float f; } v; v.u = ((unsigned)h) << 16;
    return v.f;
}

__device__ __forceinline__ void gl_lds16(const void* g, void* l) {
    __builtin_amdgcn_global_load_lds(
        (const __attribute__((address_space(1))) unsigned int*)g,
        (__attribute__((address_space(3))) unsigned int*)l, 16, 0, 0);
}

// ============ bf16 MFMA GEMM: C = act(scale * A @ Bt^T + bias) ==============
// A: [M x K] bf16 row-major; Bt: [N x K] bf16 row-major (k contiguous)
// out: Cf (f32) and/or Ch (bf16); trans=1 -> Ch[col*ldc + row] (bf16 only)
// ACT (COMPILE-TIME template param -- runtime act polluted the register
// allocation of every instantiation with the trig path; R6 post-mortem):
//   0=none 1=relu 2=elu 3=elu->*sqrt(D)+positional-encoding (fused scale_pe)
// 2-phase double-buffered K-loop: STAGE(t+1) issued before compute(t),
// single barrier per K-step. Tile shape chosen per-call so grid >= 256 blocks.
template <int BM, int BN, int WROWS, int WCOLS, int ACT>
__global__ __launch_bounds__(256) void mfma_gemm(
    const unsigned short* __restrict__ Ag, const unsigned short* __restrict__ Btg,
    const float* __restrict__ bias,
    float* __restrict__ Cfg, unsigned short* __restrict__ Chg, int trans,
    int K, int lda, int ldb, int ldc,
    int inner, long sAo, long sAi, long sBo, long sBi, long sCo, long sCi,
    float scale)
{
    constexpr int TM = BM / WROWS, TN = BN / WCOLS;
    constexpr int MT = TM / 16, NT = TN / 16;

    int z  = blockIdx.z;
    int zo = z / inner;
    int zi = z - zo * inner;
    const unsigned short* Ab = Ag + (long)zo * sAo + (long)zi * sAi;
    const unsigned short* Bt = Btg + (long)zo * sBo + (long)zi * sBi;
    long co = (long)zo * sCo + (long)zi * sCi;

    int bm = blockIdx.y * BM;
    int bn = blockIdx.x * BN;
    int tid  = threadIdx.x;
    int lane = tid & 63;
    int w    = tid >> 6;
    int wr   = w / WCOLS, wc = w - wr * WCOLS;

    __shared__ unsigned short As[2][BM * 32];
    __shared__ unsigned short Bs[2][BN * 32];

    f4_t acc[MT][NT] = {};

    int lrow = lane & 15;
    int koff = (lane >> 4) * 8;

    auto stage = [&](int buf, int k0) {
#pragma unroll
        for (int t = w; t < BM / 16; t += 4) {
            int s = t * 512 + lane * 8;
            int r = s >> 5, c = s & 31;
            gl_lds16(Ab + (long)(bm + r) * lda + k0 + c, &As[buf][t * 512]);
        }
#pragma unroll
        for (int t = w; t < BN / 16; t += 4) {
            int s = t * 512 + lane * 8;
            int r = s >> 5, c = s & 31;
            gl_lds16(Bt + (long)(bn + r) * ldb + k0 + c, &Bs[buf][t * 512]);
        }
    };

    int nk = K >> 5;
    stage(0, 0);
    __syncthreads();

    for (int t = 0; t < nk; t++) {
        int cur = t & 1;
        if (t + 1 < nk) stage(cur ^ 1, (t + 1) << 5);

        bf8_t af[MT], bfr[NT];
#pragma unroll
        for (int mi = 0; mi < MT; mi++)
            af[mi] = *(const bf8_t*)&As[cur][(wr * TM + mi * 16 + lrow) * 32 + koff];
#pragma unroll
        for (int ni = 0; ni < NT; ni++)
            bfr[ni] = *(const bf8_t*)&Bs[cur][(wc * TN + ni * 16 + lrow) * 32 + koff];
#pragma unroll
        for (int mi = 0; mi < MT; mi++)
#pragma unroll
            for (int ni = 0; ni < NT; ni++)
                acc[mi][ni] = __builtin_amdgcn_mfma_f32_16x16x32_bf16(
                    af[mi], bfr[ni], acc[mi][ni], 0, 0, 0);
        __syncthreads();   // drains prefetch (vmcnt) + reads; buf swap safe
    }

#pragma unroll
    for (int mi = 0; mi < MT; mi++) {
#pragma unroll
        for (int ni = 0; ni < NT; ni++) {
            int row0 = bm + wr * TM + mi * 16 + (lane >> 4) * 4;
            int col  = bn + wc * TN + ni * 16 + (lane & 15);
            float bv = bias ? bias[col] : 0.f;
            float vv[4];
#pragma unroll
            for (int r = 0; r < 4; r++) {
                float v = acc[mi][ni][r] * scale + bv;
                if (ACT == 1) v = fmaxf(v, 0.f);
                else if (ACT == 2) v = v > 0.f ? v : (__expf(v) - 1.f);
                else if (ACT == 3) {
                    // elu -> x*sqrt(D) + PE (fused scale_pe; n = row0+r, d = col)
                    v = v > 0.f ? v : (__expf(v) - 1.f);
                    float expo = (float)(col & ~1) * (1.0f / D_);
                    float inv  = __expf(-expo * 9.210340371976184f);   // 10000^-expo
                    float ang  = (float)(row0 + r) * inv;
                    v = v * 16.0f + ((col & 1) ? cosf(ang) : sinf(ang));
                }
                vv[r] = v;
            }
            if (trans) {
                ushort4 u = make_ushort4(f2bf(vv[0]), f2bf(vv[1]), f2bf(vv[2]), f2bf(vv[3]));
                *(ushort4*)&Chg[co + (long)col * ldc + row0] = u;
            } else {
                if (Cfg) {
#pragma unroll
                    for (int r = 0; r < 4; r++)
                        Cfg[co + (long)(row0 + r) * ldc + col] = vv[r];
                }
                if (Chg) {
#pragma unroll
                    for (int r = 0; r < 4; r++)
                        Chg[co + (long)(row0 + r) * ldc + col] = f2bf(vv[r]);
                }
            }
        }
    }
}

// ==== fused GEMM + residual-add LayerNorm ====================================
// C = A @ Bt^T + bias ; v = C + resid ; out = LN_row(v) * g + beta
// BM=32, BN=256 (full rows per block) so the LN reduction is intra-block.
// grid = (M/32); 4 waves, each owns all 32 rows x 64 cols.
__global__ __launch_bounds__(256) void mfma_gemm_ln(
    const unsigned short* __restrict__ Ag, const unsigned short* __restrict__ Btg,
    const float* __restrict__ bias,
    const float* __restrict__ resid,
    const float* __restrict__ g, const float* __restrict__ beta,
    float* __restrict__ outf, unsigned short* __restrict__ outb,
    int K)
{
    int bm = blockIdx.x * 32;
    int tid = threadIdx.x, lane = tid & 63, w = tid >> 6;
    int lrow = lane & 15, quad = lane >> 4;
    int koff = quad * 8;

    __shared__ unsigned short As[2][32 * 32];
    __shared__ unsigned short Bs[2][256 * 32];
    __shared__ float rsum[4][32];
    __shared__ float rsq[4][32];

    f4_t acc[2][4] = {};

    auto stage = [&](int buf, int k0) {
        if (w < 2) {
            int s = w * 512 + lane * 8;
            int r = s >> 5, c = s & 31;
            gl_lds16(Ag + (long)(bm + r) * K + k0 + c, &As[buf][w * 512]);
        }
#pragma unroll
        for (int t = w; t < 16; t += 4) {
            int s = t * 512 + lane * 8;
            int r = s >> 5, c = s & 31;
            gl_lds16(Btg + (long)r * K + k0 + c, &Bs[buf][t * 512]);
        }
    };

    int nk = K >> 5;
    stage(0, 0);
    __syncthreads();
    for (int t = 0; t < nk; t++) {
        int cur = t & 1;
        if (t + 1 < nk) stage(cur ^ 1, (t + 1) << 5);
        bf8_t af[2], bfr[4];
#pragma unroll
        for (int mi = 0; mi < 2; mi++)
            af[mi] = *(const bf8_t*)&As[cur][(mi * 16 + lrow) * 32 + koff];
#pragma unroll
        for (int ni = 0; ni < 4; ni++)
            bfr[ni] = *(const bf8_t*)&Bs[cur][(w * 64 + ni * 16 + lrow) * 32 + koff];
#pragma unroll
        for (int mi = 0; mi < 2; mi++)
#pragma unroll
            for (int ni = 0; ni < 4; ni++)
                acc[mi][ni] = __builtin_amdgcn_mfma_f32_16x16x32_bf16(
                    af[mi], bfr[ni], acc[mi][ni], 0, 0, 0);
        __syncthreads();
    }

    // ---- v = C + bias + resid; per-row mean (two-pass LN, matches ln_add) ---
    float vv[2][4][4];
    float sp[2][4] = {};
#pragma unroll
    for (int mi = 0; mi < 2; mi++)
#pragma unroll
        for (int ni = 0; ni < 4; ni++) {
            int row = mi * 16 + quad * 4;
            int col = w * 64 + ni * 16 + lrow;
            float bcol = bias[col];
#pragma unroll
            for (int r = 0; r < 4; r++) {
                float v = acc[mi][ni][r] + bcol +
                          resid[(long)(bm + row + r) * 256 + col];
                vv[mi][ni][r] = v;
                sp[mi][r] += v;
            }
        }
#pragma unroll
    for (int mi = 0; mi < 2; mi++)
#pragma unroll
        for (int r = 0; r < 4; r++) {
            float s = sp[mi][r];
            s += __shfl_xor(s, 1); s += __shfl_xor(s, 2);
            s += __shfl_xor(s, 4); s += __shfl_xor(s, 8);
            sp[mi][r] = s;
        }
    if (lrow == 0) {
#pragma unroll
        for (int mi = 0; mi < 2; mi++)
#pragma unroll
            for (int r = 0; r < 4; r++)
                rsum[w][mi * 16 + quad * 4 + r] = sp[mi][r];
    }
    __syncthreads();
    float mean[2][4];
#pragma unroll
    for (int mi = 0; mi < 2; mi++)
#pragma unroll
        for (int r = 0; r < 4; r++) {
            int row = mi * 16 + quad * 4 + r;
            mean[mi][r] = (rsum[0][row] + rsum[1][row] + rsum[2][row] + rsum[3][row])
                          * (1.f / 256.f);
        }
    float qp[2][4] = {};
#pragma unroll
    for (int mi = 0; mi < 2; mi++)
#pragma unroll
        for (int ni = 0; ni < 4; ni++)
#pragma unroll
            for (int r = 0; r < 4; r++) {
                float d = vv[mi][ni][r] - mean[mi][r];
                qp[mi][r] += d * d;
            }
#pragma unroll
    for (int mi = 0; mi < 2; mi++)
#pragma unroll
        for (int r = 0; r < 4; r++) {
            float s = qp[mi][r];
            s += __shfl_xor(s, 1); s += __shfl_xor(s, 2);
            s += __shfl_xor(s, 4); s += __shfl_xor(s, 8);
            qp[mi][r] = s;
        }
    if (lrow == 0) {
#pragma unroll
        for (int mi = 0; mi < 2; mi++)
#pragma unroll
            for (int r = 0; r < 4; r++)
                rsq[w][mi * 16 + quad * 4 + r] = qp[mi][r];
    }
    __syncthreads();
    float rstd[2][4];
#pragma unroll
    for (int mi = 0; mi < 2; mi++)
#pragma unroll
        for (int r = 0; r < 4; r++) {
            int row = mi * 16 + quad * 4 + r;
            float var = (rsq[0][row] + rsq[1][row] + rsq[2][row] + rsq[3][row])
                        * (1.f / 256.f);
            rstd[mi][r] = rsqrtf(var + 1e-6f);
        }
#pragma unroll
    for (int mi = 0; mi < 2; mi++)
#pragma unroll
        for (int ni = 0; ni < 4; ni++) {
            int col = w * 64 + ni * 16 + lrow;
            float gc = g[col], bc2 = beta[col];
#pragma unroll
            for (int r = 0; r < 4; r++) {
                long orow = bm + mi * 16 + quad * 4 + r;
                float o = (vv[mi][ni][r] - mean[mi][r]) * rstd[mi][r] * gc + bc2;
                outf[orow * 256 + col] = o;
                if (outb) outb[orow * 256 + col] = f2bf(o);
            }
        }
}

// ============ fused attention: scores -> mask -> softmax -> PV ==============
// QKV: [B*N][768] bf16 (Q cols 0..255, K 256..511, V 512..767)
// one workgroup = (b,h) x 64-query tile; 4 waves x 16 rows.
template <bool WRITE_ATTN>
__global__ __launch_bounds__(256) void attn_fused(
    const unsigned short* __restrict__ QKV,
    const int* __restrict__ mask,
    float* __restrict__ attn_out,            // [B,H,N,N] f32
    unsigned short* __restrict__ Ob)         // [B*N][256] bf16
{
    int bh = blockIdx.x;
    int b  = bh >> 3, h = bh & 7;
    int q0 = blockIdx.y * 64;
    int tid  = threadIdx.x;
    int lane = tid & 63, w = tid >> 6;
    int lrow = lane & 15, quad = lane >> 4;

    __shared__ unsigned short Ks[512 * 40];   // K tile, row stride 40 (padded)
    __shared__ unsigned short Vs[32 * 136];   // V^T chunk, row stride 136
    __shared__ float maskf[512];
    unsigned short* Ps = Ks;                  // P staging aliases dead K tile

    const long tokbase = (long)b * N_;

    // ---- stage K tile [512][32] ----
#pragma unroll
    for (int i = 0; i < 8; i++) {
        int idx = tid + i * 256;
        int row = idx >> 2, seg = idx & 3;
        us8 v = *(const us8*)&QKV[(tokbase + row) * 768 + 256 + h * 32 + seg * 8];
        *(us8*)&Ks[row * 40 + seg * 8] = v;
    }
    maskf[tid]       = (float)mask[b * N_ + tid] * NEG_INF_;
    maskf[tid + 256] = (float)mask[b * N_ + tid + 256] * NEG_INF_;

    // ---- Q fragment (A-operand, one per wave-row-set) ----
    bf8_t aq = *(const bf8_t*)&QKV[(tokbase + q0 + w * 16 + lrow) * 768 + h * 32 + quad * 8];
    __syncthreads();

    // ---- S = Q @ K^T (16 rows x 512 cols per wave) ----
    f4_t acc[32];
    f4_t zero = {0.f, 0.f, 0.f, 0.f};
#pragma unroll
    for (int ni = 0; ni < 32; ni++) {
        bf8_t bk = *(const bf8_t*)&Ks[(ni * 16 + lrow) * 40 + quad * 8];
        acc[ni] = __builtin_amdgcn_mfma_f32_16x16x32_bf16(aq, bk, zero, 0, 0, 0);
    }

    // ---- scale + mask + softmax (rows live in (quad, reg)) ----
    const float rscale = 0.17677669529663687f;   // 1/sqrt(32)
    float mr[4] = {-3e38f, -3e38f, -3e38f, -3e38f};
#pragma unroll
    for (int ni = 0; ni < 32; ni++) {
        float mk = maskf[ni * 16 + lrow];
#pragma unroll
        for (int r = 0; r < 4; r++) {
            float v = acc[ni][r] * rscale + mk;
            acc[ni][r] = v;
            mr[r] = fmaxf(mr[r], v);
        }
    }
#pragma unroll
    for (int r = 0; r < 4; r++) {
        mr[r] = fmaxf(mr[r], __shfl_xor(mr[r], 1));
        mr[r] = fmaxf(mr[r], __shfl_xor(mr[r], 2));
        mr[r] = fmaxf(mr[r], __shfl_xor(mr[r], 4));
        mr[r] = fmaxf(mr[r], __shfl_xor(mr[r], 8));
    }
    float sr[4] = {0.f, 0.f, 0.f, 0.f};
#pragma unroll
    for (int ni = 0; ni < 32; ni++) {
#pragma unroll
        for (int r = 0; r < 4; r++) {
            float p = __expf(acc[ni][r] - mr[r]);
            acc[ni][r] = p;
            sr[r] += p;
        }
    }
#pragma unroll
    for (int r = 0; r < 4; r++) {
        sr[r] += __shfl_xor(sr[r], 1);
        sr[r] += __shfl_xor(sr[r], 2);
        sr[r] += __shfl_xor(sr[r], 4);
        sr[r] += __shfl_xor(sr[r], 8);
        sr[r] = 1.f / sr[r];
    }
#pragma unroll
    for (int ni = 0; ni < 32; ni++)
#pragma unroll
        for (int r = 0; r < 4; r++)
            acc[ni][r] *= sr[r];

    if (WRITE_ATTN) {
#pragma unroll
        for (int ni = 0; ni < 32; ni++) {
#pragma unroll
            for (int r = 0; r < 4; r++)
                attn_out[((long)bh * N_ + q0 + w * 16 + quad * 4 + r) * N_ + ni * 16 + lrow]
                    = acc[ni][r];
        }
    }

    // ---- O = P @ V, chunks of 128 keys ----
    f4_t oacc[2] = {{0.f,0.f,0.f,0.f}, {0.f,0.f,0.f,0.f}};
    int kk4 = (tid & 31) * 4;          // 4 consecutive keys
    int d0  = (tid >> 5) * 4;          // 4 consecutive d
    for (int c = 0; c < 4; c++) {
        __syncthreads();   // prev chunk MFMA done (and, at c=0, all Ks reads done)
        {   // stage V^T chunk: Vs[d][kk] = V[c*128+kk][d]
            // per-thread: 4 rows x 4 d -> 4x4 register transpose -> 4 ds_write_b64
            us4 vr[4];
#pragma unroll
            for (int i = 0; i < 4; i++)
                vr[i] = *(const us4*)&QKV[(tokbase + c * 128 + kk4 + i) * 768
                                          + 512 + h * 32 + d0];
#pragma unroll
            for (int jj = 0; jj < 4; jj++) {
                us4 wv = { vr[0][jj], vr[1][jj], vr[2][jj], vr[3][jj] };
                *(us4*)&Vs[(d0 + jj) * 136 + kk4] = wv;
            }
        }
        // write this wave's P chunk (wave-private region, C-layout -> A-layout)
#pragma unroll
        for (int ni = 0; ni < 8; ni++) {
            int nn = c * 8 + ni;
#pragma unroll
            for (int r = 0; r < 4; r++)
                Ps[w * 2176 + (quad * 4 + r) * 136 + ni * 16 + lrow] = f2bf(acc[nn][r]);
        }
        __syncthreads();
#pragma unroll
        for (int k8 = 0; k8 < 4; k8++) {
            bf8_t ap = *(const bf8_t*)&Ps[w * 2176 + lrow * 136 + k8 * 32 + quad * 8];
#pragma unroll
            for (int t = 0; t < 2; t++) {
                bf8_t bvf = *(const bf8_t*)&Vs[(t * 16 + lrow) * 136 + k8 * 32 + quad * 8];
                oacc[t] = __builtin_amdgcn_mfma_f32_16x16x32_bf16(ap, bvf, oacc[t], 0, 0, 0);
            }
        }
    }

#pragma unroll
    for (int t = 0; t < 2; t++)
#pragma unroll
        for (int r = 0; r < 4; r++)
            Ob[(tokbase + q0 + w * 16 + quad * 4 + r) * 256 + h * 32 + t * 16 + lrow]
                = f2bf(oacc[t][r]);
}

// ======== weight transpose + f32->bf16 conversion (+ bias pack, z==13) =======
struct ConvJobs {
    const float* src[13];
    unsigned short* dst[13];
    int R[13];
    int C[13];
    const float *bq, *bk, *bv;
    float* bc;
};

__global__ __launch_bounds__(256) void conv_transpose(ConvJobs j)
{
    int z = blockIdx.z;
    if (z == 13) {
        // pack bq|bk|bv -> bc [L][768] (one block's worth of work)
        if (blockIdx.x == 0 && blockIdx.y == 0) {
            for (int i = threadIdx.x; i < 2 * 768; i += 256) {
                int l = i / 768, c = i - l * 768;
                float v = (c < 256) ? j.bq[l * 256 + c]
                        : (c < 512) ? j.bk[l * 256 + c - 256]
                                    : j.bv[l * 256 + c - 512];
                j.bc[i] = v;
            }
        }
        return;
    }
    int R = j.R[z], C = j.C[z];
    int r0 = blockIdx.y * 64, c0 = blockIdx.x * 64;
    if (r0 >= R || c0 >= C) return;
    __shared__ float t[64][65];
    const float* src = j.src[z];
    unsigned short* dst = j.dst[z];
    int tx = threadIdx.x & 63, ty = threadIdx.x >> 6;
#pragma unroll
    for (int i = 0; i < 16; i++) {
        int r = ty + i * 4;
        t[r][tx] = src[(long)(r0 + r) * C + c0 + tx];
    }
    __syncthreads();
#pragma unroll
    for (int i = 0; i < 16; i++) {
        int c = ty + i * 4;
        dst[(long)(c0 + c) * R + r0 + tx] = f2bf(t[tx][c]);
    }
}

// ============ embedding gather -> Xb bf16 (f32 copy was dead) ================
__global__ __launch_bounds__(64) void gather_embed(const int* __restrict__ idx,
                                                   const float* __restrict__ embed,
                                                   unsigned short* __restrict__ Xb)
{
    int row = blockIdx.x;
    int id  = idx[row];
    float4 v = ((const float4*)(embed + (long)id * D_))[threadIdx.x];
    ((ushort4*)(Xb + (long)row * D_))[threadIdx.x] =
        make_ushort4(f2bf(v.x), f2bf(v.y), f2bf(v.z), f2bf(v.w));
}

// ============ GAT s1/s2 from transposed h (bf16 [D][B*N]) ====================
__global__ __launch_bounds__(256) void gat_s12T(const unsigned short* __restrict__ hT,
                                                const float* __restrict__ a1,
                                                const float* __restrict__ a2,
                                                float* __restrict__ s1,
                                                float* __restrict__ s2)
{
    int lane = threadIdx.x & 63;
    int dq   = threadIdx.x >> 6;
    int j = blockIdx.x * 64 + lane;
    float d1 = 0.f, d2 = 0.f;
#pragma unroll 8
    for (int d = dq * 64; d < dq * 64 + 64; d++) {
        float hv = bf2f(hT[(long)d * (B_ * N_) + j]);
        d1 += hv * a1[d];
        d2 += hv * a2[d];
    }
    __shared__ float r1[4][64], r2[4][64];
    r1[dq][lane] = d1;
    r2[dq][lane] = d2;
    __syncthreads();
    if (dq == 0) {
        s1[j] = r1[0][lane] + r1[1][lane] + r1[2][lane] + r1[3][lane];
        s2[j] = r2[0][lane] + r2[1][lane] + r2[2][lane] + r2[3][lane];
    }
}

// ============ GAT softmax row -> bf16 alpha ==================================
__global__ __launch_bounds__(256) void gat_alpha(const float* __restrict__ s1,
                                                 const float* __restrict__ s2,
                                                 const int* __restrict__ edges,
                                                 unsigned short* __restrict__ alpha)
{
    int row = blockIdx.x;
    int b   = row >> 9;
    const int*   erow = edges + (long)row * N_;
    const float* s2b  = s2 + (long)b * N_;
    float si = s1[row];
    int t = threadIdx.x;

    float e  = si + s2b[t];
    e = e > 0.f ? e : LRELU_ * e;
    float v0 = (erow[t] > 0) ? e : NEG_INF_;
    float e2 = si + s2b[t + 256];
    e2 = e2 > 0.f ? e2 : LRELU_ * e2;
    float v1 = (erow[t + 256] > 0) ? e2 : NEG_INF_;

    __shared__ float redm[4], reds[4];
    float m = fmaxf(v0, v1);
    for (int off = 32; off; off >>= 1) m = fmaxf(m, __shfl_xor(m, off));
    if ((t & 63) == 0) redm[t >> 6] = m;
    __syncthreads();
    m = fmaxf(fmaxf(redm[0], redm[1]), fmaxf(redm[2], redm[3]));
    float x0 = __expf(v0 - m), x1 = __expf(v1 - m);
    float s = x0 + x1;
    for (int off = 32; off; off >>= 1) s += __shfl_xor(s, off);
    if ((t & 63) == 0) reds[t >> 6] = s;
    __syncthreads();
    s = reds[0] + reds[1] + reds[2] + reds[3];
    float inv = 1.f / s;
    alpha[(long)row * N_ + t]       = f2bf(x0 * inv);
    alpha[(long)row * N_ + t + 256] = f2bf(x1 * inv);
}

// ============ driver =========================================================
extern "C" void kernel_launch(void* const* d_in, const int* in_sizes, int n_in,
                              void* d_out, int out_size, void* d_ws, size_t ws_size,
                              hipStream_t stream)
{
    const int*   node  = (const int*)d_in[0];
    const int*   edge  = (const int*)d_in[1];
    const int*   mask  = (const int*)d_in[2];
    const float* embed = (const float*)d_in[4];
    const float* Wg    = (const float*)d_in[5];
    const float* a1    = (const float*)d_in[6];
    const float* a2    = (const float*)d_in[7];
    const float* Wq    = (const float*)d_in[8];
    const float* bq    = (const float*)d_in[9];
    const float* Wk    = (const float*)d_in[10];
    const float* bk    = (const float*)d_in[11];
    const float* Wv    = (const float*)d_in[12];
    const float* bv    = (const float*)d_in[13];
    const float* Wo    = (const float*)d_in[14];
    const float* bo    = (const float*)d_in[15];
    const float* W1    = (const float*)d_in[16];
    const float* b1    = (const float*)d_in[17];
    const float* W2    = (const float*)d_in[18];
    const float* b2    = (const float*)d_in[19];
    const float* ln1g  = (const float*)d_in[20];
    const float* ln1b  = (const float*)d_in[21];
    const float* ln2g  = (const float*)d_in[22];
    const float* ln2b  = (const float*)d_in[23];

    const long XSZ = (long)B_ * N_ * D_;          // 2,097,152
    const int  MR  = B_ * N_;                     // 8192
    float* outx = (float*)d_out;
    float* ATT  = outx + XSZ;                     // [B,H,N,N] f32 (final attn)

    // ---- workspace layout ----
    float*          X    = (float*)d_ws;
    unsigned short* Xb   = (unsigned short*)(X + XSZ);
    float*          Hb   = (float*)(Xb + XSZ);
    unsigned short* alphab = (unsigned short*)Hb;             // GAT alpha aliases Hb
    unsigned short* QKVb = (unsigned short*)(Hb + XSZ);       // [8192][768] bf16
    unsigned short* hT   = QKVb;                              // GAT h^T aliases QKV
    unsigned short* Ob   = QKVb + (long)MR * 768;
    unsigned short* Fb   = Ob + XSZ;                          // [8192][1024] bf16
    float* S1 = (float*)(Fb + (long)MR * DFF_);
    float* S2 = S1 + MR;
    unsigned short* WgT = (unsigned short*)(S2 + MR);         // [256][256]
    unsigned short* Wc  = WgT + 65536;                        // [L][768][256]
    unsigned short* WoT = Wc + 2 * 768 * 256;                 // [L][256][256]
    unsigned short* W1T = WoT + 2 * 65536;                    // [L][1024][256]
    unsigned short* W2T = W1T + 2 * 262144;                   // [L][256][1024]
    float*          bc  = (float*)(W2T + 2 * 262144);         // [L][768]

    // ---- convert + transpose all weights to bf16 (+ bias pack as z=13) ----
    ConvJobs j;
    j.src[0] = Wg;  j.dst[0] = WgT;  j.R[0] = 256;  j.C[0] = 256;
    for (int l = 0; l < 2; l++) {
        j.src[1 + l] = Wq + l * 65536;  j.dst[1 + l] = Wc + l * 196608;           j.R[1+l] = 256;  j.C[1+l] = 256;
        j.src[3 + l] = Wk + l * 65536;  j.dst[3 + l] = Wc + l * 196608 + 65536;   j.R[3+l] = 256;  j.C[3+l] = 256;
        j.src[5 + l] = Wv + l * 65536;  j.dst[5 + l] = Wc + l * 196608 + 131072;  j.R[5+l] = 256;  j.C[5+l] = 256;
        j.src[7 + l] = Wo + l * 65536;  j.dst[7 + l] = WoT + l * 65536;           j.R[7+l] = 256;  j.C[7+l] = 256;
        j.src[9 + l] = W1 + l * 262144; j.dst[9 + l] = W1T + l * 262144;          j.R[9+l] = 256;  j.C[9+l] = 1024;
        j.src[11+ l] = W2 + l * 262144; j.dst[11+ l] = W2T + l * 262144;          j.R[11+l]= 1024; j.C[11+l]= 256;
    }
    j.bq = bq; j.bk = bk; j.bv = bv; j.bc = bc;
    conv_transpose<<<dim3(16, 16, 14), 256, 0, stream>>>(j);

    // ---- embedding (bf16 only; f32 copy was dead) ----
    gather_embed<<<MR, 64, 0, stream>>>(node, embed, Xb);

    // ---- GAT hops ----
    for (int hop = 0; hop < 2; hop++) {
        // h = X @ Wg -> hT (trans): 256 blocks
        mfma_gemm<64,128,1,4,0><<<dim3(2, 128, 1), 256, 0, stream>>>(
            Xb, WgT, nullptr, nullptr, hT, 1,
            256, 256, 256, MR, 1, 0,0, 0,0, 0,0, 1.f);
        gat_s12T<<<128, 256, 0, stream>>>(hT, a1, a2, S1, S2);
        gat_alpha<<<MR, 256, 0, stream>>>(S1, S2, edge, alphab);
        // hop 0: x = elu(alpha @ h) -> Xb only (f32 X was dead)
        // hop 1: x = elu(alpha @ h)*sqrt(D) + PE -> X + Xb (fused scale_pe,
        //        isolated in its own ACT=3 instantiation)
        if (hop == 0)
            mfma_gemm<64,128,1,4,2><<<dim3(2, 8, 16), 256, 0, stream>>>(
                alphab, hT, nullptr, nullptr, Xb, 0,
                512, 512, MR, 256, 1,
                (long)N_*N_, 0, (long)N_, 0, (long)N_*D_, 0, 1.f);
        else
            mfma_gemm<64,128,1,4,3><<<dim3(2, 8, 16), 256, 0, stream>>>(
                alphab, hT, nullptr, X, Xb, 0,
                512, 512, MR, 256, 1,
                (long)N_*N_, 0, (long)N_, 0, (long)N_*D_, 0, 1.f);
    }

    for (int l = 0; l < L_; l++) {
        // QKV combined projection: [8192][768] bf16; 768 blocks
        mfma_gemm<64,128,1,4,0><<<dim3(6, 128, 1), 256, 0, stream>>>(
            Xb, Wc + l * 196608, bc + l * 768, nullptr, QKVb, 0,
            256, 256, 256, 768, 1, 0,0, 0,0, 0,0, 1.f);

        // fused attention (layer 1 also writes the attn output matrix)
        if (l == L_ - 1)
            attn_fused<true><<<dim3(128, 8, 1), 256, 0, stream>>>(QKVb, mask, ATT, Ob);
        else
            attn_fused<false><<<dim3(128, 8, 1), 256, 0, stream>>>(QKVb, mask, nullptr, Ob);

        // X = LN(X + O @ Wo + bo)  -- fused GEMM+LN, 256 blocks
        mfma_gemm_ln<<<dim3(MR / 32), 256, 0, stream>>>(
            Ob, WoT + l * 65536, bo + l * D_, X,
            ln1g + l * D_, ln1b + l * D_, X, Xb, 256);

        // F = relu(X @ W1 + b1)
        mfma_gemm<128,128,2,2,1><<<dim3(8, 64, 1), 256, 0, stream>>>(
            Xb, W1T + l * 262144, b1 + l * DFF_, nullptr, Fb, 0,
            256, 256, 256, 1024, 1, 0,0, 0,0, 0,0, 1.f);
        // X = LN(X + F @ W2 + b2)  -- fused GEMM+LN (last layer -> d_out)
        if (l == L_ - 1)
            mfma_gemm_ln<<<dim3(MR / 32), 256, 0, stream>>>(
                Fb, W2T + l * 262144, b2 + l * D_, X,
                ln2g + l * D_, ln2b + l * D_, outx, nullptr, 1024);
        else
            mfma_gemm_ln<<<dim3(MR / 32), 256, 0, stream>>>(
                Fb, W2T + l * 262144, b2 + l * D_, X,
                ln2g + l * D_, ln2b + l * D_, X, Xb, 1024);
    }
}

// Round 8
// 525.959 us; speedup vs baseline: 1.1270x; 1.0100x over previous
//
#include <hip/hip_runtime.h>
#include <math.h>

#define B_    16
#define N_    512
#define D_    256
#define H_    8
#define DH_   32
#define DFF_  1024
#define L_    2
#define NEG_INF_ (-1e9f)
#define LRELU_ 0.2f

typedef __attribute__((ext_vector_type(8))) short bf8_t;
typedef __attribute__((ext_vector_type(8))) unsigned short us8;
typedef __attribute__((ext_vector_type(4))) unsigned short us4;
typedef __attribute__((ext_vector_type(4))) float f4_t;

__device__ __forceinline__ unsigned short f2bf(float f) {
    union { float f; unsigned u; } v; v.f = f;
    unsigned r = v.u + 0x7FFF + ((v.u >> 16) & 1);
    return (unsigned short)(r >> 16);
}
__device__ __forceinline__ float bf2f(unsigned short h) {
    union { unsigned u; float f; } v; v.u = ((unsigned)h) << 16;
    return v.f;
}

__device__ __forceinline__ void gl_lds16(const void* g, void* l) {
    __builtin_amdgcn_global_load_lds(
        (const __attribute__((address_space(1))) unsigned int*)g,
        (__attribute__((address_space(3))) unsigned int*)l, 16, 0, 0);
}

// ============ bf16 MFMA GEMM: C = act(scale * A @ Bt^T + bias) ==============
// A: [M x K] bf16 row-major; Bt: [N x K] bf16 row-major (k contiguous)
// out: Cf (f32) and/or Ch (bf16); trans=1 -> Ch[col*ldc + row] (bf16 only)
// ACT (COMPILE-TIME template param -- runtime act polluted the register
// allocation of every instantiation with the trig path; R6 post-mortem):
//   0=none 1=relu 2=elu 3=elu->*sqrt(D)+positional-encoding (fused scale_pe)
// 2-phase double-buffered K-loop: STAGE(t+1) issued before compute(t),
// single barrier per K-step. Tile shape chosen per-call so grid >= 256 blocks.
template <int BM, int BN, int WROWS, int WCOLS, int ACT>
__global__ __launch_bounds__(256) void mfma_gemm(
    const unsigned short* __restrict__ Ag, const unsigned short* __restrict__ Btg,
    const float* __restrict__ bias,
    float* __restrict__ Cfg, unsigned short* __restrict__ Chg, int trans,
    int K, int lda, int ldb, int ldc,
    int inner, long sAo, long sAi, long sBo, long sBi, long sCo, long sCi,
    float scale)
{
    constexpr int TM = BM / WROWS, TN = BN / WCOLS;
    constexpr int MT = TM / 16, NT = TN / 16;

    int z  = blockIdx.z;
    int zo = z / inner;
    int zi = z - zo * inner;
    const unsigned short* Ab = Ag + (long)zo * sAo + (long)zi * sAi;
    const unsigned short* Bt = Btg + (long)zo * sBo + (long)zi * sBi;
    long co = (long)zo * sCo + (long)zi * sCi;

    int bm = blockIdx.y * BM;
    int bn = blockIdx.x * BN;
    int tid  = threadIdx.x;
    int lane = tid & 63;
    int w    = tid >> 6;
    int wr   = w / WCOLS, wc = w - wr * WCOLS;

    __shared__ unsigned short As[2][BM * 32];
    __shared__ unsigned short Bs[2][BN * 32];

    f4_t acc[MT][NT] = {};

    int lrow = lane & 15;
    int koff = (lane >> 4) * 8;

    auto stage = [&](int buf, int k0) {
#pragma unroll
        for (int t = w; t < BM / 16; t += 4) {
            int s = t * 512 + lane * 8;
            int r = s >> 5, c = s & 31;
            gl_lds16(Ab + (long)(bm + r) * lda + k0 + c, &As[buf][t * 512]);
        }
#pragma unroll
        for (int t = w; t < BN / 16; t += 4) {
            int s = t * 512 + lane * 8;
            int r = s >> 5, c = s & 31;
            gl_lds16(Bt + (long)(bn + r) * ldb + k0 + c, &Bs[buf][t * 512]);
        }
    };

    int nk = K >> 5;
    stage(0, 0);
    __syncthreads();

    for (int t = 0; t < nk; t++) {
        int cur = t & 1;
        if (t + 1 < nk) stage(cur ^ 1, (t + 1) << 5);

        bf8_t af[MT], bfr[NT];
#pragma unroll
        for (int mi = 0; mi < MT; mi++)
            af[mi] = *(const bf8_t*)&As[cur][(wr * TM + mi * 16 + lrow) * 32 + koff];
#pragma unroll
        for (int ni = 0; ni < NT; ni++)
            bfr[ni] = *(const bf8_t*)&Bs[cur][(wc * TN + ni * 16 + lrow) * 32 + koff];
#pragma unroll
        for (int mi = 0; mi < MT; mi++)
#pragma unroll
            for (int ni = 0; ni < NT; ni++)
                acc[mi][ni] = __builtin_amdgcn_mfma_f32_16x16x32_bf16(
                    af[mi], bfr[ni], acc[mi][ni], 0, 0, 0);
        __syncthreads();   // drains prefetch (vmcnt) + reads; buf swap safe
    }

#pragma unroll
    for (int mi = 0; mi < MT; mi++) {
#pragma unroll
        for (int ni = 0; ni < NT; ni++) {
            int row0 = bm + wr * TM + mi * 16 + (lane >> 4) * 4;
            int col  = bn + wc * TN + ni * 16 + (lane & 15);
            float bv = bias ? bias[col] : 0.f;
            float vv[4];
#pragma unroll
            for (int r = 0; r < 4; r++) {
                float v = acc[mi][ni][r] * scale + bv;
                if (ACT == 1) v = fmaxf(v, 0.f);
                else if (ACT == 2) v = v > 0.f ? v : (__expf(v) - 1.f);
                else if (ACT == 3) {
                    // elu -> x*sqrt(D) + PE (fused scale_pe; n = row0+r, d = col)
                    v = v > 0.f ? v : (__expf(v) - 1.f);
                    float expo = (float)(col & ~1) * (1.0f / D_);
                    float inv  = __expf(-expo * 9.210340371976184f);   // 10000^-expo
                    float ang  = (float)(row0 + r) * inv;
                    v = v * 16.0f + ((col & 1) ? cosf(ang) : sinf(ang));
                }
                vv[r] = v;
            }
            if (trans) {
                ushort4 u = make_ushort4(f2bf(vv[0]), f2bf(vv[1]), f2bf(vv[2]), f2bf(vv[3]));
                *(ushort4*)&Chg[co + (long)col * ldc + row0] = u;
            } else {
                if (Cfg) {
#pragma unroll
                    for (int r = 0; r < 4; r++)
                        Cfg[co + (long)(row0 + r) * ldc + col] = vv[r];
                }
                if (Chg) {
#pragma unroll
                    for (int r = 0; r < 4; r++)
                        Chg[co + (long)(row0 + r) * ldc + col] = f2bf(vv[r]);
                }
            }
        }
    }
}

// ==== fused GEMM + residual-add LayerNorm ====================================
// C = A @ Bt^T + bias ; v = C + resid ; out = LN_row(v) * g + beta
// BM=32, BN=256 (full rows per block) so the LN reduction is intra-block.
// grid = (M/32); 4 waves, each owns all 32 rows x 64 cols.
__global__ __launch_bounds__(256) void mfma_gemm_ln(
    const unsigned short* __restrict__ Ag, const unsigned short* __restrict__ Btg,
    const float* __restrict__ bias,
    const float* __restrict__ resid,
    const float* __restrict__ g, const float* __restrict__ beta,
    float* __restrict__ outf, unsigned short* __restrict__ outb,
    int K)
{
    int bm = blockIdx.x * 32;
    int tid = threadIdx.x, lane = tid & 63, w = tid >> 6;
    int lrow = lane & 15, quad = lane >> 4;
    int koff = quad * 8;

    __shared__ unsigned short As[2][32 * 32];
    __shared__ unsigned short Bs[2][256 * 32];
    __shared__ float rsum[4][32];
    __shared__ float rsq[4][32];

    f4_t acc[2][4] = {};

    auto stage = [&](int buf, int k0) {
        if (w < 2) {
            int s = w * 512 + lane * 8;
            int r = s >> 5, c = s & 31;
            gl_lds16(Ag + (long)(bm + r) * K + k0 + c, &As[buf][w * 512]);
        }
#pragma unroll
        for (int t = w; t < 16; t += 4) {
            int s = t * 512 + lane * 8;
            int r = s >> 5, c = s & 31;
            gl_lds16(Btg + (long)r * K + k0 + c, &Bs[buf][t * 512]);
        }
    };

    int nk = K >> 5;
    stage(0, 0);
    __syncthreads();
    for (int t = 0; t < nk; t++) {
        int cur = t & 1;
        if (t + 1 < nk) stage(cur ^ 1, (t + 1) << 5);
        bf8_t af[2], bfr[4];
#pragma unroll
        for (int mi = 0; mi < 2; mi++)
            af[mi] = *(const bf8_t*)&As[cur][(mi * 16 + lrow) * 32 + koff];
#pragma unroll
        for (int ni = 0; ni < 4; ni++)
            bfr[ni] = *(const bf8_t*)&Bs[cur][(w * 64 + ni * 16 + lrow) * 32 + koff];
#pragma unroll
        for (int mi = 0; mi < 2; mi++)
#pragma unroll
            for (int ni = 0; ni < 4; ni++)
                acc[mi][ni] = __builtin_amdgcn_mfma_f32_16x16x32_bf16(
                    af[mi], bfr[ni], acc[mi][ni], 0, 0, 0);
        __syncthreads();
    }

    // ---- v = C + bias + resid; per-row mean (two-pass LN, matches ln_add) ---
    float vv[2][4][4];
    float sp[2][4] = {};
#pragma unroll
    for (int mi = 0; mi < 2; mi++)
#pragma unroll
        for (int ni = 0; ni < 4; ni++) {
            int row = mi * 16 + quad * 4;
            int col = w * 64 + ni * 16 + lrow;
            float bcol = bias[col];
#pragma unroll
            for (int r = 0; r < 4; r++) {
                float v = acc[mi][ni][r] + bcol +
                          resid[(long)(bm + row + r) * 256 + col];
                vv[mi][ni][r] = v;
                sp[mi][r] += v;
            }
        }
#pragma unroll
    for (int mi = 0; mi < 2; mi++)
#pragma unroll
        for (int r = 0; r < 4; r++) {
            float s = sp[mi][r];
            s += __shfl_xor(s, 1); s += __shfl_xor(s, 2);
            s += __shfl_xor(s, 4); s += __shfl_xor(s, 8);
            sp[mi][r] = s;
        }
    if (lrow == 0) {
#pragma unroll
        for (int mi = 0; mi < 2; mi++)
#pragma unroll
            for (int r = 0; r < 4; r++)
                rsum[w][mi * 16 + quad * 4 + r] = sp[mi][r];
    }
    __syncthreads();
    float mean[2][4];
#pragma unroll
    for (int mi = 0; mi < 2; mi++)
#pragma unroll
        for (int r = 0; r < 4; r++) {
            int row = mi * 16 + quad * 4 + r;
            mean[mi][r] = (rsum[0][row] + rsum[1][row] + rsum[2][row] + rsum[3][row])
                          * (1.f / 256.f);
        }
    float qp[2][4] = {};
#pragma unroll
    for (int mi = 0; mi < 2; mi++)
#pragma unroll
        for (int ni = 0; ni < 4; ni++)
#pragma unroll
            for (int r = 0; r < 4; r++) {
                float d = vv[mi][ni][r] - mean[mi][r];
                qp[mi][r] += d * d;
            }
#pragma unroll
    for (int mi = 0; mi < 2; mi++)
#pragma unroll
        for (int r = 0; r < 4; r++) {
            float s = qp[mi][r];
            s += __shfl_xor(s, 1); s += __shfl_xor(s, 2);
            s += __shfl_xor(s, 4); s += __shfl_xor(s, 8);
            qp[mi][r] = s;
        }
    if (lrow == 0) {
#pragma unroll
        for (int mi = 0; mi < 2; mi++)
#pragma unroll
            for (int r = 0; r < 4; r++)
                rsq[w][mi * 16 + quad * 4 + r] = qp[mi][r];
    }
    __syncthreads();
    float rstd[2][4];
#pragma unroll
    for (int mi = 0; mi < 2; mi++)
#pragma unroll
        for (int r = 0; r < 4; r++) {
            int row = mi * 16 + quad * 4 + r;
            float var = (rsq[0][row] + rsq[1][row] + rsq[2][row] + rsq[3][row])
                        * (1.f / 256.f);
            rstd[mi][r] = rsqrtf(var + 1e-6f);
        }
#pragma unroll
    for (int mi = 0; mi < 2; mi++)
#pragma unroll
        for (int ni = 0; ni < 4; ni++) {
            int col = w * 64 + ni * 16 + lrow;
            float gc = g[col], bc2 = beta[col];
#pragma unroll
            for (int r = 0; r < 4; r++) {
                long orow = bm + mi * 16 + quad * 4 + r;
                float o = (vv[mi][ni][r] - mean[mi][r]) * rstd[mi][r] * gc + bc2;
                outf[orow * 256 + col] = o;
                if (outb) outb[orow * 256 + col] = f2bf(o);
            }
        }
}

// ============ fused attention: scores -> mask -> softmax -> PV ==============
// QKV: [B*N][768] bf16 (Q cols 0..255, K 256..511, V 512..767)
// one workgroup = (b,h) x 64-query tile; 4 waves x 16 rows.
// R8 restructure: barriers 9 -> 3. Ps is WAVE-PRIVATE (no barrier needed for
// P write->read, only intra-wave lgkmcnt). V global loads issued right after
// QK^T, hidden under softmax VALU (T14). Full V^T tile + Ps live in a union
// over the dead Ks region after QK^T (52.7KB total -> still 3 blocks/CU).
template <bool WRITE_ATTN>
__global__ __launch_bounds__(256) void attn_fused(
    const unsigned short* __restrict__ QKV,
    const int* __restrict__ mask,
    float* __restrict__ attn_out,            // [B,H,N,N] f32
    unsigned short* __restrict__ Ob)         // [B*N][256] bf16
{
    int bh = blockIdx.x;
    int b  = bh >> 3, h = bh & 7;
    int q0 = blockIdx.y * 64;
    int tid  = threadIdx.x;
    int lane = tid & 63, w = tid >> 6;
    int lrow = lane & 15, quad = lane >> 4;

    // phase A: Ks[512][40] (40KB). phase B (Ks dead): Vs[32][520] (33.3KB)
    // + Ps 4 waves x [16][136] (17.4KB). union = 25344 shorts = 50.7KB.
    __shared__ unsigned short smem[25344];
    __shared__ float maskf[512];
    unsigned short* Ks = smem;                 // stride 40
    unsigned short* Vs = smem;                 // stride 520
    unsigned short* Ps = smem + 16640;         // per-wave 2176

    const long tokbase = (long)b * N_;

    // ---- stage K tile [512][32] ----
#pragma unroll
    for (int i = 0; i < 8; i++) {
        int idx = tid + i * 256;
        int row = idx >> 2, seg = idx & 3;
        us8 v = *(const us8*)&QKV[(tokbase + row) * 768 + 256 + h * 32 + seg * 8];
        *(us8*)&Ks[row * 40 + seg * 8] = v;
    }
    maskf[tid]       = (float)mask[b * N_ + tid] * NEG_INF_;
    maskf[tid + 256] = (float)mask[b * N_ + tid + 256] * NEG_INF_;

    // ---- Q fragment (A-operand, one per wave-row-set) ----
    bf8_t aq = *(const bf8_t*)&QKV[(tokbase + q0 + w * 16 + lrow) * 768 + h * 32 + quad * 8];
    __syncthreads();

    // ---- S = Q @ K^T (16 rows x 512 cols per wave) ----
    f4_t acc[32];
    f4_t zero = {0.f, 0.f, 0.f, 0.f};
#pragma unroll
    for (int ni = 0; ni < 32; ni++) {
        bf8_t bk = *(const bf8_t*)&Ks[(ni * 16 + lrow) * 40 + quad * 8];
        acc[ni] = __builtin_amdgcn_mfma_f32_16x16x32_bf16(aq, bk, zero, 0, 0, 0);
    }

    // ---- issue ALL V loads now; latency hides under softmax (T14) ----
    int kk4 = (tid & 31) * 4;          // 4 consecutive keys
    int d0  = (tid >> 5) * 4;          // 4 consecutive d
    us4 vr[16];
#pragma unroll
    for (int c = 0; c < 4; c++)
#pragma unroll
        for (int i = 0; i < 4; i++)
            vr[c * 4 + i] = *(const us4*)&QKV[(tokbase + c * 128 + kk4 + i) * 768
                                              + 512 + h * 32 + d0];

    // ---- scale + mask + softmax (rows live in (quad, reg)) ----
    const float rscale = 0.17677669529663687f;   // 1/sqrt(32)
    float mr[4] = {-3e38f, -3e38f, -3e38f, -3e38f};
#pragma unroll
    for (int ni = 0; ni < 32; ni++) {
        float mk = maskf[ni * 16 + lrow];
#pragma unroll
        for (int r = 0; r < 4; r++) {
            float v = acc[ni][r] * rscale + mk;
            acc[ni][r] = v;
            mr[r] = fmaxf(mr[r], v);
        }
    }
#pragma unroll
    for (int r = 0; r < 4; r++) {
        mr[r] = fmaxf(mr[r], __shfl_xor(mr[r], 1));
        mr[r] = fmaxf(mr[r], __shfl_xor(mr[r], 2));
        mr[r] = fmaxf(mr[r], __shfl_xor(mr[r], 4));
        mr[r] = fmaxf(mr[r], __shfl_xor(mr[r], 8));
    }
    float sr[4] = {0.f, 0.f, 0.f, 0.f};
#pragma unroll
    for (int ni = 0; ni < 32; ni++) {
#pragma unroll
        for (int r = 0; r < 4; r++) {
            float p = __expf(acc[ni][r] - mr[r]);
            acc[ni][r] = p;
            sr[r] += p;
        }
    }
#pragma unroll
    for (int r = 0; r < 4; r++) {
        sr[r] += __shfl_xor(sr[r], 1);
        sr[r] += __shfl_xor(sr[r], 2);
        sr[r] += __shfl_xor(sr[r], 4);
        sr[r] += __shfl_xor(sr[r], 8);
        sr[r] = 1.f / sr[r];
    }
#pragma unroll
    for (int ni = 0; ni < 32; ni++)
#pragma unroll
        for (int r = 0; r < 4; r++)
            acc[ni][r] *= sr[r];

    if (WRITE_ATTN) {
#pragma unroll
        for (int ni = 0; ni < 32; ni++) {
#pragma unroll
            for (int r = 0; r < 4; r++)
                attn_out[((long)bh * N_ + q0 + w * 16 + quad * 4 + r) * N_ + ni * 16 + lrow]
                    = acc[ni][r];
        }
    }

    __syncthreads();   // ALL waves done reading Ks/maskf -> region reusable

    // ---- write full V^T tile: Vs[d][kk] = V[kk][d] (4x4 reg transpose) ----
#pragma unroll
    for (int c = 0; c < 4; c++)
#pragma unroll
        for (int jj = 0; jj < 4; jj++) {
            us4 wv = { vr[c * 4 + 0][jj], vr[c * 4 + 1][jj],
                       vr[c * 4 + 2][jj], vr[c * 4 + 3][jj] };
            *(us4*)&Vs[(d0 + jj) * 520 + c * 128 + kk4] = wv;
        }
    __syncthreads();   // Vs visible to all waves

    // ---- O = P @ V: per-chunk P write (wave-private, NO barrier) + MFMA ----
    f4_t oacc[2] = {{0.f,0.f,0.f,0.f}, {0.f,0.f,0.f,0.f}};
    for (int c = 0; c < 4; c++) {
#pragma unroll
        for (int ni = 0; ni < 8; ni++) {
            int nn = c * 8 + ni;
#pragma unroll
            for (int r = 0; r < 4; r++)
                Ps[w * 2176 + (quad * 4 + r) * 136 + ni * 16 + lrow] = f2bf(acc[nn][r]);
        }
        // intra-wave LDS RAW/WAR: compiler-inserted lgkmcnt orders these
#pragma unroll
        for (int k8 = 0; k8 < 4; k8++) {
            bf8_t ap = *(const bf8_t*)&Ps[w * 2176 + lrow * 136 + k8 * 32 + quad * 8];
#pragma unroll
            for (int t = 0; t < 2; t++) {
                bf8_t bvf = *(const bf8_t*)&Vs[(t * 16 + lrow) * 520 + c * 128
                                               + k8 * 32 + quad * 8];
                oacc[t] = __builtin_amdgcn_mfma_f32_16x16x32_bf16(ap, bvf, oacc[t], 0, 0, 0);
            }
        }
    }

#pragma unroll
    for (int t = 0; t < 2; t++)
#pragma unroll
        for (int r = 0; r < 4; r++)
            Ob[(tokbase + q0 + w * 16 + quad * 4 + r) * 256 + h * 32 + t * 16 + lrow]
                = f2bf(oacc[t][r]);
}

// ======== weight transpose + f32->bf16 conversion (+ bias pack, z==13) =======
struct ConvJobs {
    const float* src[13];
    unsigned short* dst[13];
    int R[13];
    int C[13];
    const float *bq, *bk, *bv;
    float* bc;
};

__global__ __launch_bounds__(256) void conv_transpose(ConvJobs j)
{
    int z = blockIdx.z;
    if (z == 13) {
        // pack bq|bk|bv -> bc [L][768] (one block's worth of work)
        if (blockIdx.x == 0 && blockIdx.y == 0) {
            for (int i = threadIdx.x; i < 2 * 768; i += 256) {
                int l = i / 768, c = i - l * 768;
                float v = (c < 256) ? j.bq[l * 256 + c]
                        : (c < 512) ? j.bk[l * 256 + c - 256]
                                    : j.bv[l * 256 + c - 512];
                j.bc[i] = v;
            }
        }
        return;
    }
    int R = j.R[z], C = j.C[z];
    int r0 = blockIdx.y * 64, c0 = blockIdx.x * 64;
    if (r0 >= R || c0 >= C) return;
    __shared__ float t[64][65];
    const float* src = j.src[z];
    unsigned short* dst = j.dst[z];
    int tx = threadIdx.x & 63, ty = threadIdx.x >> 6;
#pragma unroll
    for (int i = 0; i < 16; i++) {
        int r = ty + i * 4;
        t[r][tx] = src[(long)(r0 + r) * C + c0 + tx];
    }
    __syncthreads();
#pragma unroll
    for (int i = 0; i < 16; i++) {
        int c = ty + i * 4;
        dst[(long)(c0 + c) * R + r0 + tx] = f2bf(t[tx][c]);
    }
}

// ============ embedding gather -> Xb bf16 (f32 copy was dead) ================
__global__ __launch_bounds__(64) void gather_embed(const int* __restrict__ idx,
                                                   const float* __restrict__ embed,
                                                   unsigned short* __restrict__ Xb)
{
    int row = blockIdx.x;
    int id  = idx[row];
    float4 v = ((const float4*)(embed + (long)id * D_))[threadIdx.x];
    ((ushort4*)(Xb + (long)row * D_))[threadIdx.x] =
        make_ushort4(f2bf(v.x), f2bf(v.y), f2bf(v.z), f2bf(v.w));
}

// ============ GAT s1/s2 from transposed h (bf16 [D][B*N]) ====================
__global__ __launch_bounds__(256) void gat_s12T(const unsigned short* __restrict__ hT,
                                                const float* __restrict__ a1,
                                                const float* __restrict__ a2,
                                                float* __restrict__ s1,
                                                float* __restrict__ s2)
{
    int lane = threadIdx.x & 63;
    int dq   = threadIdx.x >> 6;
    int j = blockIdx.x * 64 + lane;
    float d1 = 0.f, d2 = 0.f;
#pragma unroll 8
    for (int d = dq * 64; d < dq * 64 + 64; d++) {
        float hv = bf2f(hT[(long)d * (B_ * N_) + j]);
        d1 += hv * a1[d];
        d2 += hv * a2[d];
    }
    __shared__ float r1[4][64], r2[4][64];
    r1[dq][lane] = d1;
    r2[dq][lane] = d2;
    __syncthreads();
    if (dq == 0) {
        s1[j] = r1[0][lane] + r1[1][lane] + r1[2][lane] + r1[3][lane];
        s2[j] = r2[0][lane] + r2[1][lane] + r2[2][lane] + r2[3][lane];
    }
}

// ============ GAT softmax row -> bf16 alpha ==================================
__global__ __launch_bounds__(256) void gat_alpha(const float* __restrict__ s1,
                                                 const float* __restrict__ s2,
                                                 const int* __restrict__ edges,
                                                 unsigned short* __restrict__ alpha)
{
    int row = blockIdx.x;
    int b   = row >> 9;
    const int*   erow = edges + (long)row * N_;
    const float* s2b  = s2 + (long)b * N_;
    float si = s1[row];
    int t = threadIdx.x;

    float e  = si + s2b[t];
    e = e > 0.f ? e : LRELU_ * e;
    float v0 = (erow[t] > 0) ? e : NEG_INF_;
    float e2 = si + s2b[t + 256];
    e2 = e2 > 0.f ? e2 : LRELU_ * e2;
    float v1 = (erow[t + 256] > 0) ? e2 : NEG_INF_;

    __shared__ float redm[4], reds[4];
    float m = fmaxf(v0, v1);
    for (int off = 32; off; off >>= 1) m = fmaxf(m, __shfl_xor(m, off));
    if ((t & 63) == 0) redm[t >> 6] = m;
    __syncthreads();
    m = fmaxf(fmaxf(redm[0], redm[1]), fmaxf(redm[2], redm[3]));
    float x0 = __expf(v0 - m), x1 = __expf(v1 - m);
    float s = x0 + x1;
    for (int off = 32; off; off >>= 1) s += __shfl_xor(s, off);
    if ((t & 63) == 0) reds[t >> 6] = s;
    __syncthreads();
    s = reds[0] + reds[1] + reds[2] + reds[3];
    float inv = 1.f / s;
    alpha[(long)row * N_ + t]       = f2bf(x0 * inv);
    alpha[(long)row * N_ + t + 256] = f2bf(x1 * inv);
}

// ============ driver =========================================================
extern "C" void kernel_launch(void* const* d_in, const int* in_sizes, int n_in,
                              void* d_out, int out_size, void* d_ws, size_t ws_size,
                              hipStream_t stream)
{
    const int*   node  = (const int*)d_in[0];
    const int*   edge  = (const int*)d_in[1];
    const int*   mask  = (const int*)d_in[2];
    const float* embed = (const float*)d_in[4];
    const float* Wg    = (const float*)d_in[5];
    const float* a1    = (const float*)d_in[6];
    const float* a2    = (const float*)d_in[7];
    const float* Wq    = (const float*)d_in[8];
    const float* bq    = (const float*)d_in[9];
    const float* Wk    = (const float*)d_in[10];
    const float* bk    = (const float*)d_in[11];
    const float* Wv    = (const float*)d_in[12];
    const float* bv    = (const float*)d_in[13];
    const float* Wo    = (const float*)d_in[14];
    const float* bo    = (const float*)d_in[15];
    const float* W1    = (const float*)d_in[16];
    const float* b1    = (const float*)d_in[17];
    const float* W2    = (const float*)d_in[18];
    const float* b2    = (const float*)d_in[19];
    const float* ln1g  = (const float*)d_in[20];
    const float* ln1b  = (const float*)d_in[21];
    const float* ln2g  = (const float*)d_in[22];
    const float* ln2b  = (const float*)d_in[23];

    const long XSZ = (long)B_ * N_ * D_;          // 2,097,152
    const int  MR  = B_ * N_;                     // 8192
    float* outx = (float*)d_out;
    float* ATT  = outx + XSZ;                     // [B,H,N,N] f32 (final attn)

    // ---- workspace layout ----
    float*          X    = (float*)d_ws;
    unsigned short* Xb   = (unsigned short*)(X + XSZ);
    float*          Hb   = (float*)(Xb + XSZ);
    unsigned short* alphab = (unsigned short*)Hb;             // GAT alpha aliases Hb
    unsigned short* QKVb = (unsigned short*)(Hb + XSZ);       // [8192][768] bf16
    unsigned short* hT   = QKVb;                              // GAT h^T aliases QKV
    unsigned short* Ob   = QKVb + (long)MR * 768;
    unsigned short* Fb   = Ob + XSZ;                          // [8192][1024] bf16
    float* S1 = (float*)(Fb + (long)MR * DFF_);
    float* S2 = S1 + MR;
    unsigned short* WgT = (unsigned short*)(S2 + MR);         // [256][256]
    unsigned short* Wc  = WgT + 65536;                        // [L][768][256]
    unsigned short* WoT = Wc + 2 * 768 * 256;                 // [L][256][256]
    unsigned short* W1T = WoT + 2 * 65536;                    // [L][1024][256]
    unsigned short* W2T = W1T + 2 * 262144;                   // [L][256][1024]
    float*          bc  = (float*)(W2T + 2 * 262144);         // [L][768]

    // ---- convert + transpose all weights to bf16 (+ bias pack as z=13) ----
    ConvJobs j;
    j.src[0] = Wg;  j.dst[0] = WgT;  j.R[0] = 256;  j.C[0] = 256;
    for (int l = 0; l < 2; l++) {
        j.src[1 + l] = Wq + l * 65536;  j.dst[1 + l] = Wc + l * 196608;           j.R[1+l] = 256;  j.C[1+l] = 256;
        j.src[3 + l] = Wk + l * 65536;  j.dst[3 + l] = Wc + l * 196608 + 65536;   j.R[3+l] = 256;  j.C[3+l] = 256;
        j.src[5 + l] = Wv + l * 65536;  j.dst[5 + l] = Wc + l * 196608 + 131072;  j.R[5+l] = 256;  j.C[5+l] = 256;
        j.src[7 + l] = Wo + l * 65536;  j.dst[7 + l] = WoT + l * 65536;           j.R[7+l] = 256;  j.C[7+l] = 256;
        j.src[9 + l] = W1 + l * 262144; j.dst[9 + l] = W1T + l * 262144;          j.R[9+l] = 256;  j.C[9+l] = 1024;
        j.src[11+ l] = W2 + l * 262144; j.dst[11+ l] = W2T + l * 262144;          j.R[11+l]= 1024; j.C[11+l]= 256;
    }
    j.bq = bq; j.bk = bk; j.bv = bv; j.bc = bc;
    conv_transpose<<<dim3(16, 16, 14), 256, 0, stream>>>(j);

    // ---- embedding (bf16 only; f32 copy was dead) ----
    gather_embed<<<MR, 64, 0, stream>>>(node, embed, Xb);

    // ---- GAT hops ----
    for (int hop = 0; hop < 2; hop++) {
        // h = X @ Wg -> hT (trans): 256 blocks
        mfma_gemm<64,128,1,4,0><<<dim3(2, 128, 1), 256, 0, stream>>>(
            Xb, WgT, nullptr, nullptr, hT, 1,
            256, 256, 256, MR, 1, 0,0, 0,0, 0,0, 1.f);
        gat_s12T<<<128, 256, 0, stream>>>(hT, a1, a2, S1, S2);
        gat_alpha<<<MR, 256, 0, stream>>>(S1, S2, edge, alphab);
        // hop 0: x = elu(alpha @ h) -> Xb only (f32 X was dead)
        // hop 1: x = elu(alpha @ h)*sqrt(D) + PE -> X + Xb (fused scale_pe,
        //        isolated in its own ACT=3 instantiation)
        if (hop == 0)
            mfma_gemm<64,128,1,4,2><<<dim3(2, 8, 16), 256, 0, stream>>>(
                alphab, hT, nullptr, nullptr, Xb, 0,
                512, 512, MR, 256, 1,
                (long)N_*N_, 0, (long)N_, 0, (long)N_*D_, 0, 1.f);
        else
            mfma_gemm<64,128,1,4,3><<<dim3(2, 8, 16), 256, 0, stream>>>(
                alphab, hT, nullptr, X, Xb, 0,
                512, 512, MR, 256, 1,
                (long)N_*N_, 0, (long)N_, 0, (long)N_*D_, 0, 1.f);
    }

    for (int l = 0; l < L_; l++) {
        // QKV combined projection: [8192][768] bf16; 768 blocks
        mfma_gemm<64,128,1,4,0><<<dim3(6, 128, 1), 256, 0, stream>>>(
            Xb, Wc + l * 196608, bc + l * 768, nullptr, QKVb, 0,
            256, 256, 256, 768, 1, 0,0, 0,0, 0,0, 1.f);

        // fused attention (layer 1 also writes the attn output matrix)
        if (l == L_ - 1)
            attn_fused<true><<<dim3(128, 8, 1), 256, 0, stream>>>(QKVb, mask, ATT, Ob);
        else
            attn_fused<false><<<dim3(128, 8, 1), 256, 0, stream>>>(QKVb, mask, nullptr, Ob);

        // X = LN(X + O @ Wo + bo)  -- fused GEMM+LN, 256 blocks
        mfma_gemm_ln<<<dim3(MR / 32), 256, 0, stream>>>(
            Ob, WoT + l * 65536, bo + l * D_, X,
            ln1g + l * D_, ln1b + l * D_, X, Xb, 256);

        // F = relu(X @ W1 + b1)
        mfma_gemm<128,128,2,2,1><<<dim3(8, 64, 1), 256, 0, stream>>>(
            Xb, W1T + l * 262144, b1 + l * DFF_, nullptr, Fb, 0,
            256, 256, 256, 1024, 1, 0,0, 0,0, 0,0, 1.f);
        // X = LN(X + F @ W2 + b2)  -- fused GEMM+LN (last layer -> d_out)
        if (l == L_ - 1)
            mfma_gemm_ln<<<dim3(MR / 32), 256, 0, stream>>>(
                Fb, W2T + l * 262144, b2 + l * D_, X,
                ln2g + l * D_, ln2b + l * D_, outx, nullptr, 1024);
        else
            mfma_gemm_ln<<<dim3(MR / 32), 256, 0, stream>>>(
                Fb, W2T + l * 262144, b2 + l * D_, X,
                ln2g + l * D_, ln2b + l * D_, X, Xb, 1024);
    }
}